// Round 17
// baseline (485.928 us; speedup 1.0000x reference)
//
#include <hip/hip_runtime.h>

#define NG    1024
#define NN    64
#define NE    128
#define NH    8
#define ND    32
#define INDIM 256
#define NS_   48
#define EPS_  1e-6
#define BK    16

// ws: [G][H][3][NN][ND] f32 (192 MiB), then elist u16[NN][64], cnt int[NN]
// (V slab [sel=2] unused — V computed inside attn.)
#define WS_QKV_FLOATS ((size_t)NG * NH * 3 * NN * ND)
#define WS_ELIST_OFF  (WS_QKV_FLOATS * sizeof(float))
#define WS_CNT_OFF    (WS_ELIST_OFF + (size_t)NN * 64 * sizeof(unsigned short))
#define WS_NEED2      (WS_CNT_OFF + (size_t)NN * sizeof(int))

typedef _Float16 half8_t __attribute__((ext_vector_type(8)));
typedef _Float16 half4_t __attribute__((ext_vector_type(4)));
typedef float    f32x4_t __attribute__((ext_vector_type(4)));

// async global->LDS 16B per lane; LDS dest = wave-uniform base + lane*16.
__device__ __forceinline__ void async_ld16(const float* gp, float* lp) {
  __builtin_amdgcn_global_load_lds(
      (const __attribute__((address_space(1))) void*)gp,
      (__attribute__((address_space(3))) void*)lp, 16, 0, 0);
}

// ======================= Kernel A: Q/K GEMM (fp32 VALU, LOCKED CHAIN) ====
// NUMERICS LOCKED: output error is amplified ~4e8x by downstream den/z
// cancellation; threshold headroom is 1.3%. Per-element chain must stay
// k=0..255 ascending fp32 FMA + bias. FROZEN — byte-exact R10 form
// (212-219us, VGPR 60, bank conflicts 0, no spill).
__global__ __launch_bounds__(256, 2) void qkv_gemm_kernel(
    const float* __restrict__ h,
    const float* __restrict__ Wq, const float* __restrict__ bq,
    const float* __restrict__ Wk, const float* __restrict__ bk,
    float* __restrict__ ws)
{
  const int b    = blockIdx.x;          // 0..4095
  const int xcd  = b & 7;
  const int slot = b >> 3;              // 0..511
  const int rt   = xcd * 128 + (slot >> 2); // 0..1023 (64-row tiles)
  const int sel  = (slot >> 1) & 1;     // 0=Q 1=K
  const int ct   = slot & 1;            // col half: 0 -> 0..127, 1 -> 128..255
  const int tid  = threadIdx.x;

  const float* W  = (sel == 0) ? Wq : Wk;
  const float* bs = (sel == 0) ? bq : bk;

  __shared__ __align__(16) float hT[2][64][16];   // row-major A slices, 8KB
  __shared__ __align__(16) float wT[2][16][128];  // k-major B slices, 16KB

  const int ty  = tid >> 5;       // 0..7  -> rows r8..r8+7
  const int tx  = tid & 31;       // 0..31
  const int r8  = ty * 8;
  const int ca  = tx * 4;         // col group: 0..124 within the half

  const int wvid = tid >> 6;      // wave 0..3
  const int lane = tid & 63;

  float acc[8][4];
  #pragma unroll
  for (int i = 0; i < 8; ++i)
    #pragma unroll
    for (int j = 0; j < 4; ++j) acc[i][j] = 0.f;

  // DMA mappings (LDS base wave-uniform; global addr per-lane):
  const float* gA = h + ((size_t)(rt * 64 + wvid * 16 + (lane >> 2))) * INDIM
                      + (lane & 3) * 4;
  const float* gB0 = W + ((size_t)(wvid * 4 + 0 + (lane >> 5))) * (NH * ND)
                       + ct * 128 + (lane & 31) * 4;
  const float* gB1 = W + ((size_t)(wvid * 4 + 2 + (lane >> 5))) * (NH * ND)
                       + ct * 128 + (lane & 31) * 4;
  float* lA[2]  = { &hT[0][wvid * 16][0], &hT[1][wvid * 16][0] };
  float* lB0[2] = { &wT[0][wvid * 4 + 0][0], &wT[1][wvid * 4 + 0][0] };
  float* lB1[2] = { &wT[0][wvid * 4 + 2][0], &wT[1][wvid * 4 + 2][0] };

  // prologue: stage tile 0 into buffer 0
  async_ld16(gA, lA[0]);
  async_ld16(gB0, lB0[0]);
  async_ld16(gB1, lB1[0]);

  for (int kc = 0; kc < INDIM / BK; ++kc) {
    __syncthreads();   // drains tile-kc DMA; all waves done with buf kc&1^1

    if (kc + 1 < INDIM / BK) {           // stage tile kc+1 into other buffer
      const int k0n = (kc + 1) * BK;
      const int nb  = (kc + 1) & 1;
      async_ld16(gA + k0n, lA[nb]);
      async_ld16(gB0 + (size_t)k0n * (NH * ND), lB0[nb]);
      async_ld16(gB1 + (size_t)k0n * (NH * ND), lB1[nb]);
    }

    const int cb = kc & 1;
    #pragma unroll
    for (int kg = 0; kg < 4; ++kg) {
      f32x4_t a4[8];
      #pragma unroll
      for (int i = 0; i < 8; ++i)
        a4[i] = *(const f32x4_t*)&hT[cb][r8 + i][kg * 4];
      f32x4_t b4[4];
      #pragma unroll
      for (int kk = 0; kk < 4; ++kk)
        b4[kk] = *(const f32x4_t*)&wT[cb][kg * 4 + kk][ca];

      #pragma unroll
      for (int kk = 0; kk < 4; ++kk) {     // k = kc*16 + kg*4 + kk, ascending
        const f32x4_t bb = b4[kk];
        #pragma unroll
        for (int i = 0; i < 8; ++i) {
          const float ai = a4[i][kk];
          acc[i][0] += ai * bb[0];
          acc[i][1] += ai * bb[1];
          acc[i][2] += ai * bb[2];
          acc[i][3] += ai * bb[3];
        }
      }
    }
  }

  // epilogue: + bias, full-line float4 stores into ws[G][H][3][64][32]
  const int col = ct * 128 + ca;
  const int hda = col >> 5, d0a = col & 31;
  float ba4[4];
  #pragma unroll
  for (int j = 0; j < 4; ++j) ba4[j] = bs[col + j];

  #pragma unroll
  for (int i = 0; i < 8; ++i) {
    const int r = rt * 64 + r8 + i;
    const int g = r >> 6, n = r & 63;
    float* opa = ws + ((((size_t)(g * NH + hda)) * 3 + sel) * NN + n) * ND + d0a;
    *(float4*)opa = make_float4(acc[i][0] + ba4[0], acc[i][1] + ba4[1],
                                acc[i][2] + ba4[2], acc[i][3] + ba4[3]);
  }
}

// ======================= Kernel S: per-node edge lists (g/h-invariant) ====
__global__ void edge_setup_kernel(const int* __restrict__ dst,
                                  unsigned short* __restrict__ elist,
                                  int* __restrict__ cnt)
{
  const int n = threadIdx.x;
  if (n < NN) {
    int c = 0;
    for (int e = 0; e < NE; ++e) {
      if (dst[e] == n) {
        if (c < 64) elist[n * 64 + c] = (unsigned short)e;   // e-ascending
        ++c;
      }
    }
    cnt[n] = (c > 64) ? 64 : c;
  }
}

// Both-sides XOR swizzle for the QT/KT column index.
#define QSW(k, c) ((c) ^ ((((k) >> 3) & 3) << 2))

// ======================= Kernel B: attention + inline V ==================
// R16: BARRIER-FREE V phase. Diagnosis: the tail resisted pipelining (R6),
// bank-swizzle (R12), inline-V (R14), XCD remap (R15) because its cost is
// SYNCHRONIZATION latency: ~23 __syncthreads/block (16 in the V staging
// loop). Fix: each lane's MFMA A-fragment is 8 CONTIGUOUS h floats and its
// B-fragment is 8 strided Wv scalars -> load both directly global->reg,
// convert in-reg, MFMA. No V staging LDS, no V barriers; waves drift and
// latency-hide each other. Barriers 23 -> 5. Fragment values and MFMA
// kc/j order identical to R14/R15 -> V bits unchanged. LOCKED QK^T chain
// (fmaf-pinned), f64 den chain, score: byte-identical.
__global__ __launch_bounds__(256, 4) void attn_kernel(
    const float* __restrict__ h,
    const float* __restrict__ Wv, const float* __restrict__ bv,
    const float* __restrict__ ws,
    const int* __restrict__ src, const int* __restrict__ dst,
    const int* __restrict__ ns,
    const unsigned short* __restrict__ elist_g, const int* __restrict__ cnt_g,
    float* __restrict__ out)
{
  const int bid = blockIdx.x;           // 0..8191
  const int xcd = bid & 7;
  const int jj  = bid >> 3;             // 0..1023
  const int g   = xcd * 128 + (jj >> 3);
  const int hd  = jj & 7;
  const int tid = threadIdx.x;
  const int ty  = tid >> 4, tx = tid & 15;
  const int lane = tid & 63;
  const int wvid = tid >> 6;            // wave 0..3
  const int lr   = lane & 15;
  const int lg   = lane >> 4;

  __shared__ __align__(16) union {
    struct { float QT[32][68]; float KT[32][68]; } a;       // 17408 B
    float QK[64][65];                                        // 16640 B
  } uQ;
  __shared__ float  Vs[64][36];
  __shared__ float  score_s[NE];
  __shared__ int    srcs[NE];
  __shared__ double z_s[NN];
  // ~28 KB total

  // ====== Phase V (barrier-free): Vs = h[g]·Wv[:,hd·32..] + bv (MFMA) ====
  {
    f32x4_t vacc0[2], vacc1[2];
    #pragma unroll
    for (int j = 0; j < 2; ++j) {
      vacc0[j] = (f32x4_t){0.f, 0.f, 0.f, 0.f};
      vacc1[j] = (f32x4_t){0.f, 0.f, 0.f, 0.f};
    }
    const int arow = 16 * wvid + lr;    // this lane's A row
    const float* hA = h + (size_t)(g * NN + arow) * INDIM + lg * 8;
    const float* wB = Wv + (size_t)(hd * ND);

    for (int kc = 0; kc < 8; ++kc) {    // K chunks of 32, ascending
      // A fragment: 8 contiguous h floats, direct to regs
      const float4 a0 = *(const float4*)(hA + kc * 32);
      const float4 a1 = *(const float4*)(hA + kc * 32 + 4);
      half8_t ah, al;
      {
        const float av[8] = {a0.x, a0.y, a0.z, a0.w, a1.x, a1.y, a1.z, a1.w};
        #pragma unroll
        for (int q = 0; q < 8; ++q) {
          const _Float16 x = (_Float16)av[q];
          ah[q] = x;
          al[q] = (_Float16)((av[q] - (float)x) * 2048.f);
        }
      }
      #pragma unroll
      for (int j = 0; j < 2; ++j) {
        // B fragment: col = j*16+lr, k = kc*32 + lg*8 + q (stride NH*ND)
        half8_t bh, bl;
        #pragma unroll
        for (int q = 0; q < 8; ++q) {
          const float w = wB[(size_t)(kc * 32 + lg * 8 + q) * (NH * ND)
                             + j * 16 + lr];
          const _Float16 x = (_Float16)w;
          bh[q] = x;
          bl[q] = (_Float16)((w - (float)x) * 2048.f);
        }
        vacc0[j] = __builtin_amdgcn_mfma_f32_16x16x32_f16(
            ah, bh, vacc0[j], 0, 0, 0);
        vacc1[j] = __builtin_amdgcn_mfma_f32_16x16x32_f16(
            ah, bl, vacc1[j], 0, 0, 0);
        vacc1[j] = __builtin_amdgcn_mfma_f32_16x16x32_f16(
            al, bh, vacc1[j], 0, 0, 0);
      }
    }

    // epilogue: D layout col=lane&15, row=(lane>>4)*4+r (m89)
    #pragma unroll
    for (int j = 0; j < 2; ++j) {
      const float bvj = bv[hd * ND + j * 16 + lr];
      #pragma unroll
      for (int r = 0; r < 4; ++r)
        Vs[16 * wvid + lg * 4 + r][j * 16 + lr] =
            vacc0[j][r] + vacc1[j][r] * (1.0f / 2048.0f) + bvj;
    }
  }
  // no barrier needed yet: QT/KT is separate LDS; Vs visibility is covered
  // by the barrier below (Vs only read in the output phase, much later).

  // ---- load Q,K (k-major, col-swizzled) from ws ----
  const float* base = ws + ((size_t)(g * NH + hd)) * 3 * (NN * ND);
  {
    const int nr = tid >> 3;
    const int d4 = (tid & 7) * 4;
    #pragma unroll
    for (int half = 0; half < 2; ++half) {
      const int n = half * 32 + nr;
      float4 q = *(const float4*)(base + (size_t)n * ND + d4);
      float4 k = *(const float4*)(base + (size_t)(NN * ND) + (size_t)n * ND + d4);
      uQ.a.QT[d4 + 0][QSW(d4 + 0, n)] = q.x;
      uQ.a.QT[d4 + 1][QSW(d4 + 1, n)] = q.y;
      uQ.a.QT[d4 + 2][QSW(d4 + 2, n)] = q.z;
      uQ.a.QT[d4 + 3][QSW(d4 + 3, n)] = q.w;
      uQ.a.KT[d4 + 0][QSW(d4 + 0, n)] = k.x;
      uQ.a.KT[d4 + 1][QSW(d4 + 1, n)] = k.y;
      uQ.a.KT[d4 + 2][QSW(d4 + 2, n)] = k.z;
      uQ.a.KT[d4 + 3][QSW(d4 + 3, n)] = k.w;
    }
  }
  __syncthreads();   // QT/KT + Vs visible

  // ---- QK[s][t] = clip(Q[s]·K[t], -5, 5)  (LOCKED chain, fmaf-pinned) ----
  {
    const int s0 = ty * 4, t0 = tx * 4;
    float qk[4][4];
    #pragma unroll
    for (int i = 0; i < 4; ++i)
      #pragma unroll
      for (int j = 0; j < 4; ++j) qk[i][j] = 0.f;
    #pragma unroll
    for (int k = 0; k < ND; ++k) {
      float4 qa = *(const float4*)&uQ.a.QT[k][QSW(k, s0)];
      float4 kb = *(const float4*)&uQ.a.KT[k][QSW(k, t0)];
      qk[0][0] = __builtin_fmaf(qa.x, kb.x, qk[0][0]);
      qk[0][1] = __builtin_fmaf(qa.x, kb.y, qk[0][1]);
      qk[0][2] = __builtin_fmaf(qa.x, kb.z, qk[0][2]);
      qk[0][3] = __builtin_fmaf(qa.x, kb.w, qk[0][3]);
      qk[1][0] = __builtin_fmaf(qa.y, kb.x, qk[1][0]);
      qk[1][1] = __builtin_fmaf(qa.y, kb.y, qk[1][1]);
      qk[1][2] = __builtin_fmaf(qa.y, kb.z, qk[1][2]);
      qk[1][3] = __builtin_fmaf(qa.y, kb.w, qk[1][3]);
      qk[2][0] = __builtin_fmaf(qa.z, kb.x, qk[2][0]);
      qk[2][1] = __builtin_fmaf(qa.z, kb.y, qk[2][1]);
      qk[2][2] = __builtin_fmaf(qa.z, kb.z, qk[2][2]);
      qk[2][3] = __builtin_fmaf(qa.z, kb.w, qk[2][3]);
      qk[3][0] = __builtin_fmaf(qa.w, kb.x, qk[3][0]);
      qk[3][1] = __builtin_fmaf(qa.w, kb.y, qk[3][1]);
      qk[3][2] = __builtin_fmaf(qa.w, kb.z, qk[3][2]);
      qk[3][3] = __builtin_fmaf(qa.w, kb.w, qk[3][3]);
    }
    __syncthreads();   // all QT/KT reads done before QK overwrites region
    #pragma unroll
    for (int i = 0; i < 4; ++i)
      #pragma unroll
      for (int j = 0; j < 4; ++j) {
        float v = qk[i][j];
        v = fminf(5.f, fmaxf(-5.f, v));
        uQ.QK[s0 + i][t0 + j] = v;
      }
  }
  __syncthreads();

  // ---- per-edge score (double den, j-ascending chain)  (LOCKED) ----
  if (tid < NE) {
    const int e = tid;
    const int s = src[e];
    srcs[e] = s;
    const float num = uQ.QK[s][dst[e]];
    double den = 0.0;
    const int* np_ = ns + (size_t)e * NS_;
    #pragma unroll
    for (int j = 0; j < NS_; ++j) den += (double)uQ.QK[s][np_[j]];
    score_s[e] = (float)((double)num / (den + (double)EPS_));
  }
  __syncthreads();

  // ---- per-node z (e-ascending double chain via precomputed edge lists) ----
  if (tid < NN) {
    const int cn = cnt_g[tid];
    double zz = 0.0;
    for (int c = 0; c < cn; ++c)
      zz += (double)score_s[elist_g[tid * 64 + c]];
    z_s[tid] = zz;
  }
  __syncthreads();

  // ---- weighted segment sum + output ----
  {
    const int n  = tid >> 2;
    const int d0 = (tid & 3) * 8;
    float wvv[8];
    #pragma unroll
    for (int i = 0; i < 8; ++i) wvv[i] = 0.f;
    const int cn = cnt_g[n];
    for (int c = 0; c < cn; ++c) {
      const int e  = elist_g[n * 64 + c];
      const float sc = score_s[e];
      const int s  = srcs[e];
      float4 v0 = *(const float4*)&Vs[s][d0];
      float4 v1 = *(const float4*)&Vs[s][d0 + 4];
      wvv[0] += sc * v0.x; wvv[1] += sc * v0.y; wvv[2] += sc * v0.z; wvv[3] += sc * v0.w;
      wvv[4] += sc * v1.x; wvv[5] += sc * v1.y; wvv[6] += sc * v1.z; wvv[7] += sc * v1.w;
    }
    const double zz = z_s[n] + (double)EPS_;
    float o[8];
    #pragma unroll
    for (int i = 0; i < 8; ++i) o[i] = (float)((double)wvv[i] / zz);
    float* op = out + (((size_t)(g * NN + n)) * NH + hd) * ND + d0;
    *(float4*)(op)     = make_float4(o[0], o[1], o[2], o[3]);
    *(float4*)(op + 4) = make_float4(o[4], o[5], o[6], o[7]);
  }
}

// ======================= Fallback: fused kernel (R2) =======================
__global__ __launch_bounds__(256, 4) void raal_fused_kernel(
    const float* __restrict__ h,
    const float* __restrict__ Wq, const float* __restrict__ bq,
    const float* __restrict__ Wk, const float* __restrict__ bk,
    const float* __restrict__ Wv, const float* __restrict__ bv,
    const int*   __restrict__ src, const int* __restrict__ dst,
    const int*   __restrict__ ns,
    float* __restrict__ out)
{
  const int hd  = blockIdx.x;
  const int g   = blockIdx.y;
  const int tid = threadIdx.x;
  const int ty  = tid >> 4, tx = tid & 15;

  __shared__ union {
    struct { float QT[32][64]; float KT[32][64]; } s2;
    float QK[64][64];
  } uQ;
  __shared__ float Vs[64][32];
  __shared__ union {
    struct { float hT[BK][68]; float wT[BK][100]; } s1;
    struct { float score[NE]; int srcs[NE]; int dsts[NE];
             double z[NN]; unsigned short elist[NN][64]; int cnt[NN]; } s3;
  } uA;

  const int r0 = ty * 4;
  const int c4 = tx * 4;
  const int cv = tx * 2;

  float accqk[4][4], accv[4][2];
  #pragma unroll
  for (int i = 0; i < 4; ++i) {
    #pragma unroll
    for (int j = 0; j < 4; ++j) accqk[i][j] = 0.f;
    accv[i][0] = 0.f; accv[i][1] = 0.f;
  }

  const int lr  = tid >> 2;
  const int lk4 = (tid & 3) * 4;
  const int wr  = ty;
  const int wc  = tx * 2;
  const float* hrow = h + ((size_t)(g * NN + lr)) * INDIM + lk4;
  const size_t wcol = (size_t)hd * ND + wc;

  float4 hv; float2 wq2, wk2, wv2;
  {
    hv  = *(const float4*)(hrow);
    const size_t wro = (size_t)wr * (NH * ND) + wcol;
    wq2 = *(const float2*)(Wq + wro);
    wk2 = *(const float2*)(Wk + wro);
    wv2 = *(const float2*)(Wv + wro);
  }

  for (int kc = 0; kc < INDIM / BK; ++kc) {
    __syncthreads();
    uA.s1.hT[lk4 + 0][lr] = hv.x;
    uA.s1.hT[lk4 + 1][lr] = hv.y;
    uA.s1.hT[lk4 + 2][lr] = hv.z;
    uA.s1.hT[lk4 + 3][lr] = hv.w;
    *(float2*)&uA.s1.wT[wr][ 0 + wc] = wq2;
    *(float2*)&uA.s1.wT[wr][32 + wc] = wk2;
    *(float2*)&uA.s1.wT[wr][64 + wc] = wv2;
    __syncthreads();

    if (kc + 1 < INDIM / BK) {
      const int k0n = (kc + 1) * BK;
      hv  = *(const float4*)(hrow + k0n);
      const size_t wro = (size_t)(k0n + wr) * (NH * ND) + wcol;
      wq2 = *(const float2*)(Wq + wro);
      wk2 = *(const float2*)(Wk + wro);
      wv2 = *(const float2*)(Wv + wro);
    }

    #pragma unroll
    for (int k = 0; k < BK; ++k) {
      float4 a  = *(const float4*)&uA.s1.hT[k][r0];
      float4 b  = *(const float4*)&uA.s1.wT[k][c4];
      float2 bv2 = *(const float2*)&uA.s1.wT[k][64 + cv];
      #pragma unroll
      for (int i = 0; i < 4; ++i) {
        const float ai = (i == 0) ? a.x : (i == 1) ? a.y : (i == 2) ? a.z : a.w;
        accqk[i][0] += ai * b.x;
        accqk[i][1] += ai * b.y;
        accqk[i][2] += ai * b.z;
        accqk[i][3] += ai * b.w;
        accv[i][0]  += ai * bv2.x;
        accv[i][1]  += ai * bv2.y;
      }
    }
  }

  {
    if (tx < 8) {
      #pragma unroll
      for (int j = 0; j < 4; ++j) {
        const int c = c4 + j;
        const float b = bq[hd * ND + c];
        #pragma unroll
        for (int i = 0; i < 4; ++i) uQ.s2.QT[c][r0 + i] = accqk[i][j] + b;
      }
    } else {
      #pragma unroll
      for (int j = 0; j < 4; ++j) {
        const int c = c4 - 32 + j;
        const float b = bk[hd * ND + c];
        #pragma unroll
        for (int i = 0; i < 4; ++i) uQ.s2.KT[c][r0 + i] = accqk[i][j] + b;
      }
    }
    const float b0 = bv[hd * ND + cv], b1 = bv[hd * ND + cv + 1];
    #pragma unroll
    for (int i = 0; i < 4; ++i) {
      Vs[r0 + i][cv]     = accv[i][0] + b0;
      Vs[r0 + i][cv + 1] = accv[i][1] + b1;
    }
  }
  __syncthreads();

  {
    const int s0 = ty * 4, t0 = tx * 4;
    float qk[4][4];
    #pragma unroll
    for (int i = 0; i < 4; ++i)
      #pragma unroll
      for (int j = 0; j < 4; ++j) qk[i][j] = 0.f;
    #pragma unroll
    for (int k = 0; k < ND; ++k) {
      float4 qa = *(const float4*)&uQ.s2.QT[k][s0];
      float4 kb = *(const float4*)&uQ.s2.KT[k][t0];
      qk[0][0] += qa.x * kb.x; qk[0][1] += qa.x * kb.y; qk[0][2] += qa.x * kb.z; qk[0][3] += qa.x * kb.w;
      qk[1][0] += qa.y * kb.x; qk[1][1] += qa.y * kb.y; qk[1][2] += qa.y * kb.z; qk[1][3] += qa.y * kb.w;
      qk[2][0] += qa.z * kb.x; qk[2][1] += qa.z * kb.y; qk[2][2] += qa.z * kb.z; qk[2][3] += qa.z * kb.w;
      qk[3][0] += qa.w * kb.x; qk[3][1] += qa.w * kb.y; qk[3][2] += qa.w * kb.z; qk[3][3] += qa.w * kb.w;
    }
    __syncthreads();
    #pragma unroll
    for (int i = 0; i < 4; ++i)
      #pragma unroll
      for (int j = 0; j < 4; ++j) {
        float v = qk[i][j];
        v = fminf(5.f, fmaxf(-5.f, v));
        uQ.QK[s0 + i][t0 + j] = v;
      }
  }
  __syncthreads();

  if (tid < NE) {
    const int e = tid;
    const int s = src[e], dd = dst[e];
    uA.s3.srcs[e] = s; uA.s3.dsts[e] = dd;
    const float num = uQ.QK[s][dd];
    double den = 0.0;
    const int* np_ = ns + (size_t)e * NS_;
    #pragma unroll
    for (int j = 0; j < NS_; ++j) den += (double)uQ.QK[s][np_[j]];
    uA.s3.score[e] = (float)((double)num / (den + (double)EPS_));
  }
  __syncthreads();

  if (tid < NN) {
    int c = 0; double zz = 0.0;
    for (int e = 0; e < NE; ++e) {
      if (uA.s3.dsts[e] == tid) {
        zz += (double)uA.s3.score[e];
        if (c < 64) uA.s3.elist[tid][c] = (unsigned short)e;
        ++c;
      }
    }
    uA.s3.cnt[tid] = (c > 64) ? 64 : c;
    uA.s3.z[tid]   = zz;
  }
  __syncthreads();

  {
    const int n  = tid >> 2;
    const int d0 = (tid & 3) * 8;
    float wvv[8];
    #pragma unroll
    for (int i = 0; i < 8; ++i) wvv[i] = 0.f;
    const int cn = uA.s3.cnt[n];
    for (int c = 0; c < cn; ++c) {
      const int e  = uA.s3.elist[n][c];
      const float sc = uA.s3.score[e];
      const int s  = uA.s3.srcs[e];
      float4 v0 = *(const float4*)&Vs[s][d0];
      float4 v1 = *(const float4*)&Vs[s][d0 + 4];
      wvv[0] += sc * v0.x; wvv[1] += sc * v0.y; wvv[2] += sc * v0.z; wvv[3] += sc * v0.w;
      wvv[4] += sc * v1.x; wvv[5] += sc * v1.y; wvv[6] += sc * v1.z; wvv[7] += sc * v1.w;
    }
    const double zz = uA.s3.z[n] + (double)EPS_;
    float o[8];
    #pragma unroll
    for (int i = 0; i < 8; ++i) o[i] = (float)((double)wvv[i] / zz);
    float* op = out + (((size_t)(g * NN + n)) * NH + hd) * ND + d0;
    *(float4*)(op)     = make_float4(o[0], o[1], o[2], o[3]);
    *(float4*)(op + 4) = make_float4(o[4], o[5], o[6], o[7]);
  }
}

extern "C" void kernel_launch(void* const* d_in, const int* in_sizes, int n_in,
                              void* d_out, int out_size, void* d_ws, size_t ws_size,
                              hipStream_t stream) {
  const float* h   = (const float*)d_in[0];
  const float* Wq  = (const float*)d_in[1];
  const float* bq  = (const float*)d_in[2];
  const float* Wk  = (const float*)d_in[3];
  const float* bk  = (const float*)d_in[4];
  const float* Wv  = (const float*)d_in[5];
  const float* bv  = (const float*)d_in[6];
  const int*   src = (const int*)d_in[7];
  const int*   dst = (const int*)d_in[8];
  const int*   ns  = (const int*)d_in[9];
  float* out = (float*)d_out;

  dim3 b(256, 1, 1);
  if (ws_size >= WS_NEED2) {
    float* ws = (float*)d_ws;
    unsigned short* elist = (unsigned short*)((char*)d_ws + WS_ELIST_OFF);
    int* cnt = (int*)((char*)d_ws + WS_CNT_OFF);

    hipLaunchKernelGGL(qkv_gemm_kernel, dim3(4096, 1, 1), b, 0, stream,
                       h, Wq, bq, Wk, bk, ws);
    hipLaunchKernelGGL(edge_setup_kernel, dim3(1, 1, 1), dim3(64, 1, 1), 0, stream,
                       dst, elist, cnt);
    hipLaunchKernelGGL(attn_kernel, dim3(NH * NG, 1, 1), b, 0, stream,
                       h, Wv, bv, ws, src, dst, ns, elist, cnt, out);
  } else {
    hipLaunchKernelGGL(raal_fused_kernel, dim3(NH, NG, 1), b, 0, stream,
                       h, Wq, bq, Wk, bk, Wv, bv, src, dst, ns, out);
  }
}

// Round 18
// 447.311 us; speedup vs baseline: 1.0863x; 1.0863x over previous
//
#include <hip/hip_runtime.h>

#define NG    1024
#define NN    64
#define NE    128
#define NH    8
#define ND    32
#define INDIM 256
#define NS_   48
#define EPS_  1e-6
#define BK    16

// MFMA V-GEMM tile params (best-measured: 128x128, R9 config @ 448.55us)
#define GBM   128
#define GBN   128
#define GBK   64

// ws: [G][H][3][NN][ND] f32 (192 MiB), then elist u16[NN][64], cnt int[NN]
#define WS_QKV_FLOATS ((size_t)NG * NH * 3 * NN * ND)
#define WS_ELIST_OFF  (WS_QKV_FLOATS * sizeof(float))
#define WS_CNT_OFF    (WS_ELIST_OFF + (size_t)NN * 64 * sizeof(unsigned short))
#define WS_NEED2      (WS_CNT_OFF + (size_t)NN * sizeof(int))

typedef _Float16 half8_t __attribute__((ext_vector_type(8)));
typedef _Float16 half4_t __attribute__((ext_vector_type(4)));
typedef float    f32x4_t __attribute__((ext_vector_type(4)));

// async global->LDS 16B per lane; LDS dest = wave-uniform base + lane*16.
__device__ __forceinline__ void async_ld16(const float* gp, float* lp) {
  __builtin_amdgcn_global_load_lds(
      (const __attribute__((address_space(1))) void*)gp,
      (__attribute__((address_space(3))) void*)lp, 16, 0, 0);
}

// ======================= Kernel A: Q/K GEMM (fp32 VALU, LOCKED CHAIN) ====
// NUMERICS LOCKED: output error is amplified ~4e8x by downstream den/z
// cancellation; threshold headroom is 1.3%. Per-element chain must stay
// k=0..255 ascending fp32 FMA + bias. FROZEN: best form (R7 DMA staging +
// R9 4-k unroll). 212-219us, VGPR 60, bank conflicts 0, no spill; within
// ~35% of VALU-issue bound across five structural variants (occupancy,
// spill, LDS-instruction count, barrier structure all proven non-levers).
__global__ __launch_bounds__(256, 2) void qkv_gemm_kernel(
    const float* __restrict__ h,
    const float* __restrict__ Wq, const float* __restrict__ bq,
    const float* __restrict__ Wk, const float* __restrict__ bk,
    float* __restrict__ ws)
{
  const int b    = blockIdx.x;          // 0..4095
  const int xcd  = b & 7;
  const int slot = b >> 3;              // 0..511
  const int rt   = xcd * 128 + (slot >> 2); // 0..1023 (64-row tiles)
  const int sel  = (slot >> 1) & 1;     // 0=Q 1=K
  const int ct   = slot & 1;            // col half: 0 -> 0..127, 1 -> 128..255
  const int tid  = threadIdx.x;

  const float* W  = (sel == 0) ? Wq : Wk;
  const float* bs = (sel == 0) ? bq : bk;

  __shared__ __align__(16) float hT[2][64][16];   // row-major A slices, 8KB
  __shared__ __align__(16) float wT[2][16][128];  // k-major B slices, 16KB

  const int ty  = tid >> 5;       // 0..7  -> rows r8..r8+7
  const int tx  = tid & 31;       // 0..31
  const int r8  = ty * 8;
  const int ca  = tx * 4;         // col group: 0..124 within the half

  const int wvid = tid >> 6;      // wave 0..3
  const int lane = tid & 63;

  float acc[8][4];
  #pragma unroll
  for (int i = 0; i < 8; ++i)
    #pragma unroll
    for (int j = 0; j < 4; ++j) acc[i][j] = 0.f;

  // DMA mappings (LDS base wave-uniform; global addr per-lane):
  const float* gA = h + ((size_t)(rt * 64 + wvid * 16 + (lane >> 2))) * INDIM
                      + (lane & 3) * 4;
  const float* gB0 = W + ((size_t)(wvid * 4 + 0 + (lane >> 5))) * (NH * ND)
                       + ct * 128 + (lane & 31) * 4;
  const float* gB1 = W + ((size_t)(wvid * 4 + 2 + (lane >> 5))) * (NH * ND)
                       + ct * 128 + (lane & 31) * 4;
  float* lA[2]  = { &hT[0][wvid * 16][0], &hT[1][wvid * 16][0] };
  float* lB0[2] = { &wT[0][wvid * 4 + 0][0], &wT[1][wvid * 4 + 0][0] };
  float* lB1[2] = { &wT[0][wvid * 4 + 2][0], &wT[1][wvid * 4 + 2][0] };

  // prologue: stage tile 0 into buffer 0
  async_ld16(gA, lA[0]);
  async_ld16(gB0, lB0[0]);
  async_ld16(gB1, lB1[0]);

  for (int kc = 0; kc < INDIM / BK; ++kc) {
    __syncthreads();   // drains tile-kc DMA; all waves done with buf kc&1^1

    if (kc + 1 < INDIM / BK) {           // stage tile kc+1 into other buffer
      const int k0n = (kc + 1) * BK;
      const int nb  = (kc + 1) & 1;
      async_ld16(gA + k0n, lA[nb]);
      async_ld16(gB0 + (size_t)k0n * (NH * ND), lB0[nb]);
      async_ld16(gB1 + (size_t)k0n * (NH * ND), lB1[nb]);
    }

    const int cb = kc & 1;
    #pragma unroll
    for (int kg = 0; kg < 4; ++kg) {
      f32x4_t a4[8];
      #pragma unroll
      for (int i = 0; i < 8; ++i)
        a4[i] = *(const f32x4_t*)&hT[cb][r8 + i][kg * 4];
      f32x4_t b4[4];
      #pragma unroll
      for (int kk = 0; kk < 4; ++kk)
        b4[kk] = *(const f32x4_t*)&wT[cb][kg * 4 + kk][ca];

      #pragma unroll
      for (int kk = 0; kk < 4; ++kk) {     // k = kc*16 + kg*4 + kk, ascending
        const f32x4_t bb = b4[kk];
        #pragma unroll
        for (int i = 0; i < 8; ++i) {
          const float ai = a4[i][kk];
          acc[i][0] += ai * bb[0];
          acc[i][1] += ai * bb[1];
          acc[i][2] += ai * bb[2];
          acc[i][3] += ai * bb[3];
        }
      }
    }
  }

  // epilogue: + bias, full-line float4 stores into ws[G][H][3][64][32]
  const int col = ct * 128 + ca;
  const int hda = col >> 5, d0a = col & 31;
  float ba4[4];
  #pragma unroll
  for (int j = 0; j < 4; ++j) ba4[j] = bs[col + j];

  #pragma unroll
  for (int i = 0; i < 8; ++i) {
    const int r = rt * 64 + r8 + i;
    const int g = r >> 6, n = r & 63;
    float* opa = ws + ((((size_t)(g * NH + hda)) * 3 + sel) * NN + n) * ND + d0a;
    *(float4*)opa = make_float4(acc[i][0] + ba4[0], acc[i][1] + ba4[1],
                                acc[i][2] + ba4[2], acc[i][3] + ba4[3]);
  }
}

// XOR-swizzled pointer into a [rows][GBK] fp16 row-major LDS tile.
// Row stride = 128 B; XOR bits 4..6 with (row&7) -> frag ds_read_b128
// conflict-free. (row&7) is per-thread constant for all fragment accesses.
__device__ __forceinline__ void* swz_pt(void* base, int row, int k) {
  size_t byte = ((size_t)(row * GBK + k)) * 2;
  byte ^= (size_t)((row & 7) << 4);
  return (void*)((char*)base + byte);
}

// ======================= Kernel V: V GEMM via split-fp16 MFMA ============
// V is NOT on the den/z-amplified path (verified R2: absmax exactly 6144).
// 2-term split (v = vh + vl*2^-11, residual exact by Sterbenz):
//   acc0 += ah*bh ; acc1 += ah*bl + al*bh ; C = acc0 + acc1*2^-11 + bias
// Best-measured form (R9 config): 128x128 tile, grid 1025 (block 1024 =
// int-only edge-setup). Convert-bound (~110us); restructures (128x64 tile,
// attn-fusion, barrier-free) all measured neutral-to-worse.
__global__ __launch_bounds__(256, 2) void v_gemm_mfma(
    const float* __restrict__ h,
    const float* __restrict__ Wv, const float* __restrict__ bv,
    const int* __restrict__ dst,
    unsigned short* __restrict__ elist, int* __restrict__ cnt,
    float* __restrict__ ws)
{
  const int b = blockIdx.x;             // 0..1024
  if (b >= 1024) {
    // edge setup (g/h-invariant)
    const int n = threadIdx.x;
    if (n < NN) {
      int c = 0;
      for (int e = 0; e < NE; ++e) {
        if (dst[e] == n) {
          if (c < 64) elist[n * 64 + c] = (unsigned short)e;  // e-ascending
          ++c;
        }
      }
      cnt[n] = (c > 64) ? 64 : c;
    }
    return;
  }

  const int xcd  = b & 7;
  const int slot = b >> 3;              // 0..127
  const int rt   = xcd * 64 + (slot >> 1); // 0..511
  const int ct   = slot & 1;            // col tile 0..1

  __shared__ __align__(16) _Float16 Ahh[GBM * GBK];
  __shared__ __align__(16) _Float16 Ahl[GBM * GBK];
  __shared__ __align__(16) _Float16 Bhh[GBN * GBK];
  __shared__ __align__(16) _Float16 Bhl[GBN * GBK];

  const int tid  = threadIdx.x;
  const int lane = tid & 63;
  const int wvid = tid >> 6;            // wave 0..3
  const int wm   = wvid >> 1;           // wave row 0..1
  const int wn   = wvid & 1;            // wave col 0..1
  const int lr   = lane & 15;           // frag row (A) / col (B,D)
  const int lg   = lane >> 4;           // k-group / D row-group

  f32x4_t acc0[4][4], acc1[4][4];
  #pragma unroll
  for (int i = 0; i < 4; ++i)
    #pragma unroll
    for (int j = 0; j < 4; ++j) {
      acc0[i][j] = (f32x4_t){0.f, 0.f, 0.f, 0.f};
      acc1[i][j] = (f32x4_t){0.f, 0.f, 0.f, 0.f};
    }

  // loader mapping
  const float* hA  = h + (size_t)rt * GBM * INDIM;
  const int bnn    = tid >> 1;                      // B col 0..127
  const int bkh    = (tid & 1) * 32;                // B k-half {0,32}
  const int c0     = ct * GBN;
  const float* wB  = Wv + (size_t)bkh * (NH * ND) + (c0 + bnn);

  for (int kc = 0; kc < INDIM / GBK; ++kc) {
    // global loads to regs first (overlap latency across the sync)
    float4 av4[8];
    #pragma unroll
    for (int i = 0; i < 8; ++i) {
      const int idx = i * 256 + tid;
      const int row = idx >> 4, kq = idx & 15;
      av4[i] = *(const float4*)(hA + (size_t)row * INDIM + kc * GBK + kq * 4);
    }
    float wv32[32];
    #pragma unroll
    for (int j = 0; j < 32; ++j)
      wv32[j] = wB[(size_t)(kc * GBK + j) * (NH * ND)];

    if (kc) __syncthreads();            // prior frag reads done

    #pragma unroll
    for (int i = 0; i < 8; ++i) {
      const int idx = i * 256 + tid;
      const int row = idx >> 4, kq = idx & 15;
      half4_t ph, pl;
      ph[0] = (_Float16)av4[i].x; ph[1] = (_Float16)av4[i].y;
      ph[2] = (_Float16)av4[i].z; ph[3] = (_Float16)av4[i].w;
      pl[0] = (_Float16)((av4[i].x - (float)ph[0]) * 2048.f);
      pl[1] = (_Float16)((av4[i].y - (float)ph[1]) * 2048.f);
      pl[2] = (_Float16)((av4[i].z - (float)ph[2]) * 2048.f);
      pl[3] = (_Float16)((av4[i].w - (float)ph[3]) * 2048.f);
      *(half4_t*)swz_pt(Ahh, row, kq * 4) = ph;
      *(half4_t*)swz_pt(Ahl, row, kq * 4) = pl;
    }
    #pragma unroll
    for (int c = 0; c < 4; ++c) {
      half8_t ph, pl;
      #pragma unroll
      for (int j = 0; j < 8; ++j) {
        const float a  = wv32[c * 8 + j];
        const _Float16 x = (_Float16)a;
        ph[j] = x;
        pl[j] = (_Float16)((a - (float)x) * 2048.f);
      }
      *(half8_t*)swz_pt(Bhh, bnn, bkh + c * 8) = ph;
      *(half8_t*)swz_pt(Bhl, bnn, bkh + c * 8) = pl;
    }
    __syncthreads();

    #pragma unroll
    for (int ks = 0; ks < 2; ++ks) {
      const int kb = ks * 32 + lg * 8;
      half8_t bh[4], bl[4];
      #pragma unroll
      for (int j = 0; j < 4; ++j) {
        const int colr = wn * 64 + j * 16 + lr;
        bh[j] = *(const half8_t*)swz_pt(Bhh, colr, kb);
        bl[j] = *(const half8_t*)swz_pt(Bhl, colr, kb);
      }
      #pragma unroll
      for (int i = 0; i < 4; ++i) {
        const int rowr = wm * 64 + i * 16 + lr;
        const half8_t ah = *(const half8_t*)swz_pt(Ahh, rowr, kb);
        const half8_t al = *(const half8_t*)swz_pt(Ahl, rowr, kb);
        #pragma unroll
        for (int j = 0; j < 4; ++j) {
          acc0[i][j] = __builtin_amdgcn_mfma_f32_16x16x32_f16(
              ah, bh[j], acc0[i][j], 0, 0, 0);
          acc1[i][j] = __builtin_amdgcn_mfma_f32_16x16x32_f16(
              ah, bl[j], acc1[i][j], 0, 0, 0);
          acc1[i][j] = __builtin_amdgcn_mfma_f32_16x16x32_f16(
              al, bh[j], acc1[i][j], 0, 0, 0);
        }
      }
    }
  }

  // epilogue: combine chains, + bias, store into ws[...][sel=2][...]
  float bj[4];
  #pragma unroll
  for (int j = 0; j < 4; ++j) bj[j] = bv[c0 + wn * 64 + j * 16 + lr];

  #pragma unroll
  for (int i = 0; i < 4; ++i) {
    #pragma unroll
    for (int r = 0; r < 4; ++r) {
      const int R = rt * GBM + wm * 64 + i * 16 + lg * 4 + r;
      const int g = R >> 6, n = R & 63;
      #pragma unroll
      for (int j = 0; j < 4; ++j) {
        const int col = c0 + wn * 64 + j * 16 + lr;
        const int hd = col >> 5, d = col & 31;
        const float val = acc0[i][j][r] + acc1[i][j][r] * (1.0f / 2048.0f)
                          + bj[j];
        ws[((((size_t)(g * NH + hd)) * 3 + 2) * NN + n) * ND + d] = val;
      }
    }
  }
}

// ======================= Kernel B: attention (proven R2/R5 form) =========
// Latency-bound (VALUBusy 53%, Occ 48%, 100.7us measured R11). Resisted:
// software pipelining (R6), bank-conflict swizzle (R12, conflicts hidden
// under latency), inline-V fusion (R14), XCD-aware remap (R15),
// barrier-free V (R16, regressed). This form is the best measured.
__global__ __launch_bounds__(256, 5) void attn_kernel(
    const float* __restrict__ ws,
    const int* __restrict__ src, const int* __restrict__ dst,
    const int* __restrict__ ns,
    const unsigned short* __restrict__ elist_g, const int* __restrict__ cnt_g,
    float* __restrict__ out)
{
  const int hd  = blockIdx.x;
  const int g   = blockIdx.y;
  const int tid = threadIdx.x;
  const int ty  = tid >> 4, tx = tid & 15;

  __shared__ union {
    struct { float QT[32][68]; float KT[32][68]; } a;
    float QK[64][65];
  } uQ;
  __shared__ float Vs[64][36];
  __shared__ float  score_s[NE];
  __shared__ int    srcs[NE], dsts[NE];
  __shared__ double z_s[NN];
  // total ~28.7 KB -> 5 blocks/CU

  // ---- load Q,K (k-major) and V from ws ----
  const float* base = ws + ((size_t)(g * NH + hd)) * 3 * (NN * ND);
  {
    const int nr = tid >> 3;
    const int d4 = (tid & 7) * 4;
    #pragma unroll
    for (int half = 0; half < 2; ++half) {
      const int n = half * 32 + nr;
      float4 q = *(const float4*)(base + (size_t)n * ND + d4);
      float4 k = *(const float4*)(base + (size_t)(NN * ND) + (size_t)n * ND + d4);
      float4 v = *(const float4*)(base + (size_t)(2 * NN * ND) + (size_t)n * ND + d4);
      uQ.a.QT[d4 + 0][n] = q.x; uQ.a.QT[d4 + 1][n] = q.y;
      uQ.a.QT[d4 + 2][n] = q.z; uQ.a.QT[d4 + 3][n] = q.w;
      uQ.a.KT[d4 + 0][n] = k.x; uQ.a.KT[d4 + 1][n] = k.y;
      uQ.a.KT[d4 + 2][n] = k.z; uQ.a.KT[d4 + 3][n] = k.w;
      *(float4*)&Vs[n][d4] = v;
    }
  }
  __syncthreads();

  // ---- QK[s][t] = clip(Q[s]·K[t], -5, 5)  (LOCKED) ----
  {
    const int s0 = ty * 4, t0 = tx * 4;
    float qk[4][4];
    #pragma unroll
    for (int i = 0; i < 4; ++i)
      #pragma unroll
      for (int j = 0; j < 4; ++j) qk[i][j] = 0.f;
    #pragma unroll
    for (int k = 0; k < ND; ++k) {
      float4 qa = *(const float4*)&uQ.a.QT[k][s0];
      float4 kb = *(const float4*)&uQ.a.KT[k][t0];
      qk[0][0] += qa.x * kb.x; qk[0][1] += qa.x * kb.y; qk[0][2] += qa.x * kb.z; qk[0][3] += qa.x * kb.w;
      qk[1][0] += qa.y * kb.x; qk[1][1] += qa.y * kb.y; qk[1][2] += qa.y * kb.z; qk[1][3] += qa.y * kb.w;
      qk[2][0] += qa.z * kb.x; qk[2][1] += qa.z * kb.y; qk[2][2] += qa.z * kb.z; qk[2][3] += qa.z * kb.w;
      qk[3][0] += qa.w * kb.x; qk[3][1] += qa.w * kb.y; qk[3][2] += qa.w * kb.z; qk[3][3] += qa.w * kb.w;
    }
    __syncthreads();   // all QT/KT reads done before QK overwrites region
    #pragma unroll
    for (int i = 0; i < 4; ++i)
      #pragma unroll
      for (int j = 0; j < 4; ++j) {
        float v = qk[i][j];
        v = fminf(5.f, fmaxf(-5.f, v));
        uQ.QK[s0 + i][t0 + j] = v;
      }
  }
  __syncthreads();

  // ---- per-edge score (double den, j-ascending chain)  (LOCKED) ----
  if (tid < NE) {
    const int e = tid;
    const int s = src[e], dd = dst[e];
    srcs[e] = s; dsts[e] = dd;
    const float num = uQ.QK[s][dd];
    double den = 0.0;
    const int* np_ = ns + (size_t)e * NS_;
    #pragma unroll
    for (int j = 0; j < NS_; ++j) den += (double)uQ.QK[s][np_[j]];
    score_s[e] = (float)((double)num / (den + (double)EPS_));
  }
  __syncthreads();

  // ---- per-node z (e-ascending double chain via precomputed edge lists) ----
  if (tid < NN) {
    const int cn = cnt_g[tid];
    double zz = 0.0;
    for (int c = 0; c < cn; ++c)
      zz += (double)score_s[elist_g[tid * 64 + c]];
    z_s[tid] = zz;
  }
  __syncthreads();

  // ---- weighted segment sum + output ----
  {
    const int n  = tid >> 2;
    const int d0 = (tid & 3) * 8;
    float wvv[8];
    #pragma unroll
    for (int i = 0; i < 8; ++i) wvv[i] = 0.f;
    const int cn = cnt_g[n];
    for (int c = 0; c < cn; ++c) {
      const int e  = elist_g[n * 64 + c];
      const float sc = score_s[e];
      const int s  = srcs[e];
      float4 v0 = *(const float4*)&Vs[s][d0];
      float4 v1 = *(const float4*)&Vs[s][d0 + 4];
      wvv[0] += sc * v0.x; wvv[1] += sc * v0.y; wvv[2] += sc * v0.z; wvv[3] += sc * v0.w;
      wvv[4] += sc * v1.x; wvv[5] += sc * v1.y; wvv[6] += sc * v1.z; wvv[7] += sc * v1.w;
    }
    const double zz = z_s[n] + (double)EPS_;
    float o[8];
    #pragma unroll
    for (int i = 0; i < 8; ++i) o[i] = (float)((double)wvv[i] / zz);
    float* op = out + (((size_t)(g * NN + n)) * NH + hd) * ND + d0;
    *(float4*)(op)     = make_float4(o[0], o[1], o[2], o[3]);
    *(float4*)(op + 4) = make_float4(o[4], o[5], o[6], o[7]);
  }
}

// ======================= Fallback: fused kernel (R2) =======================
__global__ __launch_bounds__(256, 4) void raal_fused_kernel(
    const float* __restrict__ h,
    const float* __restrict__ Wq, const float* __restrict__ bq,
    const float* __restrict__ Wk, const float* __restrict__ bk,
    const float* __restrict__ Wv, const float* __restrict__ bv,
    const int*   __restrict__ src, const int* __restrict__ dst,
    const int*   __restrict__ ns,
    float* __restrict__ out)
{
  const int hd  = blockIdx.x;
  const int g   = blockIdx.y;
  const int tid = threadIdx.x;
  const int ty  = tid >> 4, tx = tid & 15;

  __shared__ union {
    struct { float QT[32][64]; float KT[32][64]; } s2;
    float QK[64][64];
  } uQ;
  __shared__ float Vs[64][32];
  __shared__ union {
    struct { float hT[BK][68]; float wT[BK][100]; } s1;
    struct { float score[NE]; int srcs[NE]; int dsts[NE];
             double z[NN]; unsigned short elist[NN][64]; int cnt[NN]; } s3;
  } uA;

  const int r0 = ty * 4;
  const int c4 = tx * 4;
  const int cv = tx * 2;

  float accqk[4][4], accv[4][2];
  #pragma unroll
  for (int i = 0; i < 4; ++i) {
    #pragma unroll
    for (int j = 0; j < 4; ++j) accqk[i][j] = 0.f;
    accv[i][0] = 0.f; accv[i][1] = 0.f;
  }

  const int lr  = tid >> 2;
  const int lk4 = (tid & 3) * 4;
  const int wr  = ty;
  const int wc  = tx * 2;
  const float* hrow = h + ((size_t)(g * NN + lr)) * INDIM + lk4;
  const size_t wcol = (size_t)hd * ND + wc;

  float4 hv; float2 wq2, wk2, wv2;
  {
    hv  = *(const float4*)(hrow);
    const size_t wro = (size_t)wr * (NH * ND) + wcol;
    wq2 = *(const float2*)(Wq + wro);
    wk2 = *(const float2*)(Wk + wro);
    wv2 = *(const float2*)(Wv + wro);
  }

  for (int kc = 0; kc < INDIM / BK; ++kc) {
    __syncthreads();
    uA.s1.hT[lk4 + 0][lr] = hv.x;
    uA.s1.hT[lk4 + 1][lr] = hv.y;
    uA.s1.hT[lk4 + 2][lr] = hv.z;
    uA.s1.hT[lk4 + 3][lr] = hv.w;
    *(float2*)&uA.s1.wT[wr][ 0 + wc] = wq2;
    *(float2*)&uA.s1.wT[wr][32 + wc] = wk2;
    *(float2*)&uA.s1.wT[wr][64 + wc] = wv2;
    __syncthreads();

    if (kc + 1 < INDIM / BK) {
      const int k0n = (kc + 1) * BK;
      hv  = *(const float4*)(hrow + k0n);
      const size_t wro = (size_t)(k0n + wr) * (NH * ND) + wcol;
      wq2 = *(const float2*)(Wq + wro);
      wk2 = *(const float2*)(Wk + wro);
      wv2 = *(const float2*)(Wv + wro);
    }

    #pragma unroll
    for (int k = 0; k < BK; ++k) {
      float4 a  = *(const float4*)&uA.s1.hT[k][r0];
      float4 b  = *(const float4*)&uA.s1.wT[k][c4];
      float2 bv2 = *(const float2*)&uA.s1.wT[k][64 + cv];
      #pragma unroll
      for (int i = 0; i < 4; ++i) {
        const float ai = (i == 0) ? a.x : (i == 1) ? a.y : (i == 2) ? a.z : a.w;
        accqk[i][0] += ai * b.x;
        accqk[i][1] += ai * b.y;
        accqk[i][2] += ai * b.z;
        accqk[i][3] += ai * b.w;
        accv[i][0]  += ai * bv2.x;
        accv[i][1]  += ai * bv2.y;
      }
    }
  }

  {
    if (tx < 8) {
      #pragma unroll
      for (int j = 0; j < 4; ++j) {
        const int c = c4 + j;
        const float b = bq[hd * ND + c];
        #pragma unroll
        for (int i = 0; i < 4; ++i) uQ.s2.QT[c][r0 + i] = accqk[i][j] + b;
      }
    } else {
      #pragma unroll
      for (int j = 0; j < 4; ++j) {
        const int c = c4 - 32 + j;
        const float b = bk[hd * ND + c];
        #pragma unroll
        for (int i = 0; i < 4; ++i) uQ.s2.KT[c][r0 + i] = accqk[i][j] + b;
      }
    }
    const float b0 = bv[hd * ND + cv], b1 = bv[hd * ND + cv + 1];
    #pragma unroll
    for (int i = 0; i < 4; ++i) {
      Vs[r0 + i][cv]     = accv[i][0] + b0;
      Vs[r0 + i][cv + 1] = accv[i][1] + b1;
    }
  }
  __syncthreads();

  {
    const int s0 = ty * 4, t0 = tx * 4;
    float qk[4][4];
    #pragma unroll
    for (int i = 0; i < 4; ++i)
      #pragma unroll
      for (int j = 0; j < 4; ++j) qk[i][j] = 0.f;
    #pragma unroll
    for (int k = 0; k < ND; ++k) {
      float4 qa = *(const float4*)&uQ.s2.QT[k][s0];
      float4 kb = *(const float4*)&uQ.s2.KT[k][t0];
      qk[0][0] += qa.x * kb.x; qk[0][1] += qa.x * kb.y; qk[0][2] += qa.x * kb.z; qk[0][3] += qa.x * kb.w;
      qk[1][0] += qa.y * kb.x; qk[1][1] += qa.y * kb.y; qk[1][2] += qa.y * kb.z; qk[1][3] += qa.y * kb.w;
      qk[2][0] += qa.z * kb.x; qk[2][1] += qa.z * kb.y; qk[2][2] += qa.z * kb.z; qk[2][3] += qa.z * kb.w;
      qk[3][0] += qa.w * kb.x; qk[3][1] += qa.w * kb.y; qk[3][2] += qa.w * kb.z; qk[3][3] += qa.w * kb.w;
    }
    __syncthreads();
    #pragma unroll
    for (int i = 0; i < 4; ++i)
      #pragma unroll
      for (int j = 0; j < 4; ++j) {
        float v = qk[i][j];
        v = fminf(5.f, fmaxf(-5.f, v));
        uQ.QK[s0 + i][t0 + j] = v;
      }
  }
  __syncthreads();

  if (tid < NE) {
    const int e = tid;
    const int s = src[e], dd = dst[e];
    uA.s3.srcs[e] = s; uA.s3.dsts[e] = dd;
    const float num = uQ.QK[s][dd];
    double den = 0.0;
    const int* np_ = ns + (size_t)e * NS_;
    #pragma unroll
    for (int j = 0; j < NS_; ++j) den += (double)uQ.QK[s][np_[j]];
    uA.s3.score[e] = (float)((double)num / (den + (double)EPS_));
  }
  __syncthreads();

  if (tid < NN) {
    int c = 0; double zz = 0.0;
    for (int e = 0; e < NE; ++e) {
      if (uA.s3.dsts[e] == tid) {
        zz += (double)uA.s3.score[e];
        if (c < 64) uA.s3.elist[tid][c] = (unsigned short)e;
        ++c;
      }
    }
    uA.s3.cnt[tid] = (c > 64) ? 64 : c;
    uA.s3.z[tid]   = zz;
  }
  __syncthreads();

  {
    const int n  = tid >> 2;
    const int d0 = (tid & 3) * 8;
    float wvv[8];
    #pragma unroll
    for (int i = 0; i < 8; ++i) wvv[i] = 0.f;
    const int cn = uA.s3.cnt[n];
    for (int c = 0; c < cn; ++c) {
      const int e  = uA.s3.elist[n][c];
      const float sc = uA.s3.score[e];
      const int s  = uA.s3.srcs[e];
      float4 v0 = *(const float4*)&Vs[s][d0];
      float4 v1 = *(const float4*)&Vs[s][d0 + 4];
      wvv[0] += sc * v0.x; wvv[1] += sc * v0.y; wvv[2] += sc * v0.z; wvv[3] += sc * v0.w;
      wvv[4] += sc * v1.x; wvv[5] += sc * v1.y; wvv[6] += sc * v1.z; wvv[7] += sc * v1.w;
    }
    const double zz = uA.s3.z[n] + (double)EPS_;
    float o[8];
    #pragma unroll
    for (int i = 0; i < 8; ++i) o[i] = (float)((double)wvv[i] / zz);
    float* op = out + (((size_t)(g * NN + n)) * NH + hd) * ND + d0;
    *(float4*)(op)     = make_float4(o[0], o[1], o[2], o[3]);
    *(float4*)(op + 4) = make_float4(o[4], o[5], o[6], o[7]);
  }
}

extern "C" void kernel_launch(void* const* d_in, const int* in_sizes, int n_in,
                              void* d_out, int out_size, void* d_ws, size_t ws_size,
                              hipStream_t stream) {
  const float* h   = (const float*)d_in[0];
  const float* Wq  = (const float*)d_in[1];
  const float* bq  = (const float*)d_in[2];
  const float* Wk  = (const float*)d_in[3];
  const float* bk  = (const float*)d_in[4];
  const float* Wv  = (const float*)d_in[5];
  const float* bv  = (const float*)d_in[6];
  const int*   src = (const int*)d_in[7];
  const int*   dst = (const int*)d_in[8];
  const int*   ns  = (const int*)d_in[9];
  float* out = (float*)d_out;

  dim3 b(256, 1, 1);
  if (ws_size >= WS_NEED2) {
    float* ws = (float*)d_ws;
    unsigned short* elist = (unsigned short*)((char*)d_ws + WS_ELIST_OFF);
    int* cnt = (int*)((char*)d_ws + WS_CNT_OFF);

    hipLaunchKernelGGL(qkv_gemm_kernel, dim3(4096, 1, 1), b, 0, stream,
                       h, Wq, bq, Wk, bk, ws);
    hipLaunchKernelGGL(v_gemm_mfma, dim3(1025, 1, 1), b, 0, stream,
                       h, Wv, bv, dst, elist, cnt, ws);
    hipLaunchKernelGGL(attn_kernel, dim3(NH, NG, 1), b, 0, stream,
                       ws, src, dst, ns, elist, cnt, out);
  } else {
    hipLaunchKernelGGL(raal_fused_kernel, dim3(NH, NG, 1), b, 0, stream,
                       h, Wq, bq, Wk, bk, Wv, bv, src, dst, ns, out);
  }
}